// Round 4
// baseline (178.196 us; speedup 1.0000x reference)
//
#include <hip/hip_runtime.h>
#include <hip/hip_bf16.h>

#define B_ 16
#define T_ 1024
#define D_ 512
#define H_ 8

typedef __attribute__((ext_vector_type(4))) float f32x4;
typedef __attribute__((ext_vector_type(8))) short bf16x8;
typedef __attribute__((ext_vector_type(4))) short bf16x4;
typedef __attribute__((ext_vector_type(2))) unsigned int u32x2;

__device__ __forceinline__ void gld_lds16(const void* g, void* l) {
    __builtin_amdgcn_global_load_lds((const __attribute__((address_space(1))) void*)g,
                                     (__attribute__((address_space(3))) void*)l, 16, 0, 0);
}
__device__ __forceinline__ void gld_lds4(const void* g, void* l) {
    __builtin_amdgcn_global_load_lds((const __attribute__((address_space(1))) void*)g,
                                     (__attribute__((address_space(3))) void*)l, 4, 0, 0);
}

__device__ __forceinline__ short f2bf(float f) {
    union { float f; unsigned u; } v; v.f = f;
    unsigned r = v.u + 0x7FFF + ((v.u >> 16) & 1);
    return (short)(r >> 16);
}

// ---------------- weight transpose: W fp32 [K][N] -> Wt bf16 [N][K], 3 mats ----------------
__global__ void wtrans_kernel(const float* __restrict__ Wq, const float* __restrict__ Wk,
                              const float* __restrict__ Wv, short* __restrict__ WtAll) {
    __shared__ float tile[64][65];
    const int t = threadIdx.x;
    const int mat = blockIdx.y;
    const float* W = (mat == 0) ? Wq : (mat == 1) ? Wk : Wv;
    short* Wt = WtAll + (size_t)mat * D_ * D_;
    const int kt = (blockIdx.x >> 3) * 64;
    const int nt = (blockIdx.x & 7) * 64;
#pragma unroll
    for (int i = 0; i < 4; ++i) {
        int idx = t + i * 256;
        int r = idx >> 4, c4 = idx & 15;
        float4 v = *(const float4*)&W[(kt + r) * D_ + nt + c4 * 4];
        tile[r][c4 * 4 + 0] = v.x; tile[r][c4 * 4 + 1] = v.y;
        tile[r][c4 * 4 + 2] = v.z; tile[r][c4 * 4 + 3] = v.w;
    }
    __syncthreads();
#pragma unroll
    for (int i = 0; i < 2; ++i) {
        int idx = t + i * 256;
        int nr = idx >> 3, c8 = idx & 7;
        bf16x8 pk;
#pragma unroll
        for (int j = 0; j < 8; ++j) pk[j] = f2bf(tile[c8 * 8 + j][nr]);
        *(bf16x8*)&Wt[(nt + nr) * D_ + kt + c8 * 8] = pk;
    }
}

// ---------------- padding masks (fused q+k): row sum -> onv / offv ----------------
__global__ void mask_kernel(const float* __restrict__ queries, const float* __restrict__ keys,
                            float* __restrict__ qm, float* __restrict__ kb) {
    const int w = threadIdx.x >> 6, lane = threadIdx.x & 63;
    const int row = blockIdx.x * 4 + w;
    const int which = blockIdx.y;
    const float* X = which ? keys : queries;
    const float4* p = (const float4*)&X[(size_t)row * D_];
    float s = 0.f;
#pragma unroll
    for (int i = 0; i < 2; ++i) {
        float4 v = p[lane + 64 * i];
        s += v.x + v.y + v.z + v.w;
    }
#pragma unroll
    for (int m = 1; m < 64; m <<= 1) s += __shfl_xor(s, m);
    if (lane == 0) {
        if (which) kb[row] = (s != 0.0f) ? 0.0f : -3e30f;
        else       qm[row] = (s != 0.0f) ? 1.0f : 0.0f;
    }
}

// ---------------- projection GEMM (batched over 3 mats via grid.z) ----------------
__global__ __launch_bounds__(256) void proj_gemm(
    const float* __restrict__ Xq, const float* __restrict__ Xk, const float* __restrict__ Xv,
    const short* __restrict__ WtAll,
    const float* __restrict__ bq, const float* __restrict__ bk, const float* __restrict__ bv,
    short* __restrict__ Qb, short* __restrict__ Kb, short* __restrict__ Vb) {
    __shared__ short As[128][72];
    __shared__ short Bs[128][72];
    const int t = threadIdx.x;
    const int mat = blockIdx.z;
    const float* X = (mat == 0) ? Xq : (mat == 1) ? Xk : Xv;
    const short* Wt = WtAll + (size_t)mat * D_ * D_;
    const float* bias = (mat == 0) ? bq : (mat == 1) ? bk : bv;
    short* dst = (mat == 0) ? Qb : (mat == 1) ? Kb : Vb;
    const int m0 = blockIdx.x * 128, n0 = blockIdx.y * 128;
    const int lane = t & 63, w = t >> 6;
    const int wr = w >> 1, wc = w & 1;
    const int cl = lane & 15, g = lane >> 4;
    f32x4 acc[4][4] = {};
    for (int kt = 0; kt < D_; kt += 64) {
#pragma unroll
        for (int i = 0; i < 8; ++i) {
            int idx = t + 256 * i;
            int r = idx >> 4, c4 = idx & 15;
            float4 v = *(const float4*)&X[(size_t)(m0 + r) * D_ + kt + c4 * 4];
            bf16x4 pk;
            pk[0] = f2bf(v.x); pk[1] = f2bf(v.y); pk[2] = f2bf(v.z); pk[3] = f2bf(v.w);
            *(bf16x4*)&As[r][c4 * 4] = pk;
        }
#pragma unroll
        for (int i = 0; i < 4; ++i) {
            int idx = t + 256 * i;
            int r = idx >> 3, c8 = idx & 7;
            *(bf16x8*)&Bs[r][c8 * 8] = *(const bf16x8*)&Wt[(size_t)(n0 + r) * D_ + kt + c8 * 8];
        }
        __syncthreads();
#pragma unroll
        for (int ks = 0; ks < 2; ++ks) {
            bf16x8 a[4], b[4];
#pragma unroll
            for (int m = 0; m < 4; ++m)
                a[m] = *(const bf16x8*)&As[wr * 64 + m * 16 + cl][ks * 32 + g * 8];
#pragma unroll
            for (int n = 0; n < 4; ++n)
                b[n] = *(const bf16x8*)&Bs[wc * 64 + n * 16 + cl][ks * 32 + g * 8];
#pragma unroll
            for (int m = 0; m < 4; ++m)
#pragma unroll
                for (int n = 0; n < 4; ++n)
                    acc[m][n] = __builtin_amdgcn_mfma_f32_16x16x32_bf16(a[m], b[n], acc[m][n], 0, 0, 0);
        }
        __syncthreads();
    }
#pragma unroll
    for (int n = 0; n < 4; ++n) {
        int col = n0 + wc * 64 + n * 16 + cl;
        float bv2 = bias[col];
#pragma unroll
        for (int m = 0; m < 4; ++m) {
            int rowb = m0 + wr * 64 + m * 16 + g * 4;
#pragma unroll
            for (int j = 0; j < 4; ++j)
                dst[(size_t)(rowb + j) * D_ + col] = f2bf(acc[m][n][j] + bv2);
        }
    }
}

// ---------------- V transpose: Vb [B*T][512] -> VtG [(b*8+h)*64+d][T] ----------------
__global__ void vtrans_kernel(const short* __restrict__ Vb, short* __restrict__ VtG) {
    __shared__ short tile[64][72];
    const int t = threadIdx.x;
    const int kt = blockIdx.x & 15;
    const int h  = (blockIdx.x >> 4) & 7;
    const int b  = blockIdx.x >> 7;
#pragma unroll
    for (int i = 0; i < 2; ++i) {
        int idx = t + i * 256;
        int r = idx >> 3, c8 = idx & 7;
        *(bf16x8*)&tile[((r & 7) << 3) | (r >> 3)][c8 * 8] =
            *(const bf16x8*)&Vb[(size_t)(b * T_ + kt * 64 + r) * D_ + h * 64 + c8 * 8];
    }
    __syncthreads();
#pragma unroll
    for (int i = 0; i < 2; ++i) {
        int idx = t + i * 256;
        int d = idx >> 3, r8 = idx & 7;
        bf16x8 pk;
#pragma unroll
        for (int j = 0; j < 8; ++j) pk[j] = tile[(j << 3) | r8][d];
        *(bf16x8*)&VtG[(size_t)((b * 8 + h) * 64 + d) * T_ + kt * 64 + r8 * 8] = pk;
    }
}

// ---------------- flash attention + residual: paired q-tiles, uniform work ----------------
// 8 waves (512 thr); block handles q-tiles bx and 7-bx (work = const 18 units).
__global__ __launch_bounds__(512, 4) void attn_kernel(
    const short* __restrict__ Qb, const short* __restrict__ Kb,
    const short* __restrict__ VtG, const float* __restrict__ qmask,
    const float* __restrict__ kbias, const float* __restrict__ queries,
    float* __restrict__ out) {
    // LDS: KV[buf][K 8KB | V 8KB] = 32768 | kb[2][256] @32768 | Ps[8][16][72] @33280
    __shared__ __align__(16) char lds[32768 + 512 + 8 * 16 * 72 * 2];
    const int t = threadIdx.x, lane = t & 63, w = t >> 6;
    const int cl = lane & 15, g = lane >> 4;
    const int bx = blockIdx.x, h = blockIdx.y, b = blockIdx.z;
    const int qlo = bx * 128, qhi = (7 - bx) * 128;
    const int nt = 16 - 2 * bx, lastLo = 2 * bx + 1;

    const int rS = t >> 3, cS = ((t & 7) ^ (rS & 7)) * 8;
    const short* kS = Kb + ((size_t)(b * T_) + rS) * D_ + h * 64 + cS;
    const short* vS = VtG + (size_t)((b * 8 + h) * 64 + rS) * T_ + cS;
    const float* kbp = kbias + b * T_;
    short* PsW = (short*)(lds + 33280) + w * (16 * 72);

    // Q B-fragments: col=q=cl, elems d = kc*32+g*8+j
    bf16x8 qb[2][2];
#pragma unroll
    for (int tl = 0; tl < 2; ++tl) {
        const int q0 = (tl ? qhi : qlo) + w * 16 + cl;
#pragma unroll
        for (int kc = 0; kc < 2; ++kc)
            qb[tl][kc] = *(const bf16x8*)&Qb[(size_t)(b * T_ + q0) * D_ + h * 64 + kc * 32 + g * 8];
    }

    // prologue: stage tile 0 -> buf 0
    gld_lds16(kS, lds + t * 16);
    gld_lds16(vS, lds + 8192 + t * 16);
    if (w == 0) gld_lds4(kbp + lane, lds + 32768 + lane * 4);

    f32x4 o[2][4] = {};
    float m[2] = {-3e30f, -3e30f}, l[2] = {0.f, 0.f};
    const float csc = 0.125f * 1.44269504088896f;   // 1/sqrt(64) * log2(e)

    for (int it = 0; it < nt; ++it) {
        const int buf = it & 1, kt = it * 64;
        __syncthreads();   // implicit vmcnt(0): tile staged; all waves done with buf^1

        if (it + 1 < nt) {   // prefetch next tile (flies during compute)
            const int kt2 = (it + 1) * 64;
            char* db = lds + (buf ^ 1) * 16384;
            gld_lds16(kS + (size_t)kt2 * D_, db + t * 16);
            gld_lds16(vS + kt2, db + 8192 + t * 16);
            if (w == 0) gld_lds4(kbp + kt2 + lane, lds + 32768 + (buf ^ 1) * 256 + lane * 4);
        }

        const char* Kl = lds + buf * 16384;
        const char* Vl = Kl + 8192;
        const float* KBl = (const float*)(lds + 32768 + buf * 256);
        const bool hasLo = (it <= lastLo);

        // QK^T swapped: s[tl][nc][j] = S[k = nc*16+g*4+j][q = cl]
        f32x4 s[2][4] = {};
#pragma unroll
        for (int kc = 0; kc < 2; ++kc)
#pragma unroll
            for (int nc = 0; nc < 4; ++nc) {
                bf16x8 a = *(const bf16x8*)(Kl + (nc * 16 + cl) * 128 + (((kc * 4 + g) ^ (cl & 7)) << 4));
                s[1][nc] = __builtin_amdgcn_mfma_f32_16x16x32_bf16(a, qb[1][kc], s[1][nc], 0, 0, 0);
            }
        if (hasLo) {
#pragma unroll
            for (int kc = 0; kc < 2; ++kc)
#pragma unroll
                for (int nc = 0; nc < 4; ++nc) {
                    bf16x8 a = *(const bf16x8*)(Kl + (nc * 16 + cl) * 128 + (((kc * 4 + g) ^ (cl & 7)) << 4));
                    s[0][nc] = __builtin_amdgcn_mfma_f32_16x16x32_bf16(a, qb[0][kc], s[0][nc], 0, 0, 0);
                }
        }

#pragma unroll
        for (int tl = 0; tl < 2; ++tl) {
            if (tl == 0 && !hasLo) continue;
            const int ctb = tl ? (14 - 2 * bx) : (2 * bx);
            const int qr = (tl ? qhi : qlo) + w * 16 + cl;
            const bool ct = (it >= ctb);
            float pm = -3e30f;
#pragma unroll
            for (int nc = 0; nc < 4; ++nc) {
                f32x4 kb4 = *(const f32x4*)&KBl[nc * 16 + g * 4];
#pragma unroll
                for (int j = 0; j < 4; ++j) {
                    float v = fmaf(s[tl][nc][j], csc, kb4[j]);
                    if (ct && (kt + nc * 16 + g * 4 + j > qr)) v = -3e30f;
                    s[tl][nc][j] = v;
                    pm = fmaxf(pm, v);
                }
            }
            pm = fmaxf(pm, __shfl_xor(pm, 16));
            pm = fmaxf(pm, __shfl_xor(pm, 32));
            // defer-max: skip O/l rescale while max grows < 8 (exp2 domain)
            if (__any(pm > m[tl] + 8.f)) {
                float mn = fmaxf(m[tl], pm), cf;
                asm("v_exp_f32 %0, %1" : "=v"(cf) : "v"(m[tl] - mn));
                l[tl] *= cf;
                m[tl] = mn;
#pragma unroll
                for (int j = 0; j < 4; ++j) {
                    float cfj = __shfl(cf, g * 4 + j);
#pragma unroll
                    for (int dc = 0; dc < 4; ++dc) o[tl][dc][j] *= cfj;
                }
            }
            float ps = 0.f;
#pragma unroll
            for (int nc = 0; nc < 4; ++nc)
#pragma unroll
                for (int j = 0; j < 4; ++j) {
                    float p;
                    asm("v_exp_f32 %0, %1" : "=v"(p) : "v"(s[tl][nc][j] - m[tl]));
                    s[tl][nc][j] = p;
                    ps += p;
                }
            ps += __shfl_xor(ps, 16);
            ps += __shfl_xor(ps, 32);
            l[tl] += ps;

            // P -> per-wave LDS [q=cl][k] (cvt_pk + b64)
#pragma unroll
            for (int nc = 0; nc < 4; ++nc) {
                u32x2 pw;
                asm("v_cvt_pk_bf16_f32 %0, %1, %2" : "=v"(pw[0]) : "v"(s[tl][nc][0]), "v"(s[tl][nc][1]));
                asm("v_cvt_pk_bf16_f32 %0, %1, %2" : "=v"(pw[1]) : "v"(s[tl][nc][2]), "v"(s[tl][nc][3]));
                *(u32x2*)&PsW[cl * 72 + nc * 16 + g * 4] = pw;
            }
            // PV: A = P (rows q=cl), B = V^T rows d (XOR-swizzled read)
#pragma unroll
            for (int ks = 0; ks < 2; ++ks) {
                bf16x8 pa = *(const bf16x8*)&PsW[cl * 72 + ks * 32 + g * 8];
#pragma unroll
                for (int dc = 0; dc < 4; ++dc) {
                    bf16x8 vv = *(const bf16x8*)(Vl + (dc * 16 + cl) * 128 + (((ks * 4 + g) ^ (cl & 7)) << 4));
                    o[tl][dc] = __builtin_amdgcn_mfma_f32_16x16x32_bf16(pa, vv, o[tl][dc], 0, 0, 0);
                }
            }
        }
    }

    // epilogue: normalize, query mask, residual (both q-tiles)
#pragma unroll
    for (int tl = 0; tl < 2; ++tl) {
        float inv = 1.0f / l[tl];
#pragma unroll
        for (int j = 0; j < 4; ++j) {
            float linv = __shfl(inv, g * 4 + j);
            const int q = (tl ? qhi : qlo) + w * 16 + g * 4 + j;
            const float sc2 = linv * qmask[b * T_ + q];
            const size_t base = (size_t)(b * T_ + q) * D_ + h * 64;
#pragma unroll
            for (int dc = 0; dc < 4; ++dc) {
                const size_t idx = base + dc * 16 + cl;
                out[idx] = o[tl][dc][j] * sc2 + queries[idx];
            }
        }
    }
}

extern "C" void kernel_launch(void* const* d_in, const int* in_sizes, int n_in,
                              void* d_out, int out_size, void* d_ws, size_t ws_size,
                              hipStream_t stream) {
    const float* queries = (const float*)d_in[0];
    const float* keys    = (const float*)d_in[1];
    const float* value   = (const float*)d_in[2];
    const float* Wq      = (const float*)d_in[3];
    const float* bq      = (const float*)d_in[4];
    const float* Wk      = (const float*)d_in[5];
    const float* bk      = (const float*)d_in[6];
    const float* Wv      = (const float*)d_in[7];
    const float* bv      = (const float*)d_in[8];
    float* out = (float*)d_out;

    char* ws = (char*)d_ws;
    const size_t WT_SZ  = (size_t)D_ * D_ * 2;        // 512 KB
    const size_t QKV_SZ = (size_t)B_ * T_ * D_ * 2;   // 16 MB
    short* WtAll = (short*)(ws);
    short* Qb  = (short*)(ws + 3 * WT_SZ);
    short* Kb  = (short*)(ws + 3 * WT_SZ + QKV_SZ);
    short* Vb  = (short*)(ws + 3 * WT_SZ + 2 * QKV_SZ);
    short* VtG = (short*)(ws + 3 * WT_SZ + 3 * QKV_SZ);
    float* qm  = (float*)(ws + 3 * WT_SZ + 4 * QKV_SZ);
    float* kb  = qm + B_ * T_;

    wtrans_kernel<<<dim3(64, 3), 256, 0, stream>>>(Wq, Wk, Wv, WtAll);
    mask_kernel<<<dim3(B_ * T_ / 4, 2), 256, 0, stream>>>(queries, keys, qm, kb);

    proj_gemm<<<dim3(B_ * T_ / 128, D_ / 128, 3), 256, 0, stream>>>(
        queries, keys, value, WtAll, bq, bk, bv, Qb, Kb, Vb);

    vtrans_kernel<<<B_ * H_ * (T_ / 64), 256, 0, stream>>>(Vb, VtG);

    attn_kernel<<<dim3(4, H_, B_), 512, 0, stream>>>(Qb, Kb, VtG, qm, kb, queries, out);
}

// Round 5
// 131.468 us; speedup vs baseline: 1.3554x; 1.3554x over previous
//
#include <hip/hip_runtime.h>
#include <hip/hip_bf16.h>

#define B_ 16
#define T_ 1024
#define D_ 512
#define H_ 8

typedef __attribute__((ext_vector_type(4))) float f32x4;
typedef __attribute__((ext_vector_type(8))) short bf16x8;
typedef __attribute__((ext_vector_type(4))) short bf16x4;
typedef __attribute__((ext_vector_type(2))) unsigned int u32x2;

__device__ __forceinline__ void gld_lds16(const void* g, void* l) {
    __builtin_amdgcn_global_load_lds((const __attribute__((address_space(1))) void*)g,
                                     (__attribute__((address_space(3))) void*)l, 16, 0, 0);
}

__device__ __forceinline__ short f2bf(float f) {
    union { float f; unsigned u; } v; v.f = f;
    unsigned r = v.u + 0x7FFF + ((v.u >> 16) & 1);
    return (short)(r >> 16);
}

// ---------------- weight transpose: W fp32 [K][N] -> Wt bf16 [N][K], 3 mats ----------------
__global__ void wtrans_kernel(const float* __restrict__ Wq, const float* __restrict__ Wk,
                              const float* __restrict__ Wv, short* __restrict__ WtAll) {
    __shared__ float tile[64][65];
    const int t = threadIdx.x;
    const int mat = blockIdx.y;
    const float* W = (mat == 0) ? Wq : (mat == 1) ? Wk : Wv;
    short* Wt = WtAll + (size_t)mat * D_ * D_;
    const int kt = (blockIdx.x >> 3) * 64;
    const int nt = (blockIdx.x & 7) * 64;
#pragma unroll
    for (int i = 0; i < 4; ++i) {
        int idx = t + i * 256;
        int r = idx >> 4, c4 = idx & 15;
        float4 v = *(const float4*)&W[(kt + r) * D_ + nt + c4 * 4];
        tile[r][c4 * 4 + 0] = v.x; tile[r][c4 * 4 + 1] = v.y;
        tile[r][c4 * 4 + 2] = v.z; tile[r][c4 * 4 + 3] = v.w;
    }
    __syncthreads();
#pragma unroll
    for (int i = 0; i < 2; ++i) {
        int idx = t + i * 256;
        int nr = idx >> 3, c8 = idx & 7;
        bf16x8 pk;
#pragma unroll
        for (int j = 0; j < 8; ++j) pk[j] = f2bf(tile[c8 * 8 + j][nr]);
        *(bf16x8*)&Wt[(nt + nr) * D_ + kt + c8 * 8] = pk;
    }
}

// ---------------- padding masks (fused q+k): row sum -> onv / offv ----------------
__global__ void mask_kernel(const float* __restrict__ queries, const float* __restrict__ keys,
                            float* __restrict__ qm, float* __restrict__ kb) {
    const int w = threadIdx.x >> 6, lane = threadIdx.x & 63;
    const int row = blockIdx.x * 4 + w;
    const int which = blockIdx.y;
    const float* X = which ? keys : queries;
    const float4* p = (const float4*)&X[(size_t)row * D_];
    float s = 0.f;
#pragma unroll
    for (int i = 0; i < 2; ++i) {
        float4 v = p[lane + 64 * i];
        s += v.x + v.y + v.z + v.w;
    }
#pragma unroll
    for (int m = 1; m < 64; m <<= 1) s += __shfl_xor(s, m);
    if (lane == 0) {
        if (which) kb[row] = (s != 0.0f) ? 0.0f : -3e30f;
        else       qm[row] = (s != 0.0f) ? 1.0f : 0.0f;
    }
}

// ---------------- projection GEMM (batched over 3 mats via grid.z) ----------------
__global__ __launch_bounds__(256) void proj_gemm(
    const float* __restrict__ Xq, const float* __restrict__ Xk, const float* __restrict__ Xv,
    const short* __restrict__ WtAll,
    const float* __restrict__ bq, const float* __restrict__ bk, const float* __restrict__ bv,
    short* __restrict__ Qb, short* __restrict__ Kb, short* __restrict__ Vb) {
    __shared__ short As[128][72];
    __shared__ short Bs[128][72];
    const int t = threadIdx.x;
    const int mat = blockIdx.z;
    const float* X = (mat == 0) ? Xq : (mat == 1) ? Xk : Xv;
    const short* Wt = WtAll + (size_t)mat * D_ * D_;
    const float* bias = (mat == 0) ? bq : (mat == 1) ? bk : bv;
    short* dst = (mat == 0) ? Qb : (mat == 1) ? Kb : Vb;
    const int m0 = blockIdx.x * 128, n0 = blockIdx.y * 128;
    const int lane = t & 63, w = t >> 6;
    const int wr = w >> 1, wc = w & 1;
    const int cl = lane & 15, g = lane >> 4;
    f32x4 acc[4][4] = {};
    for (int kt = 0; kt < D_; kt += 64) {
#pragma unroll
        for (int i = 0; i < 8; ++i) {
            int idx = t + 256 * i;
            int r = idx >> 4, c4 = idx & 15;
            float4 v = *(const float4*)&X[(size_t)(m0 + r) * D_ + kt + c4 * 4];
            bf16x4 pk;
            pk[0] = f2bf(v.x); pk[1] = f2bf(v.y); pk[2] = f2bf(v.z); pk[3] = f2bf(v.w);
            *(bf16x4*)&As[r][c4 * 4] = pk;
        }
#pragma unroll
        for (int i = 0; i < 4; ++i) {
            int idx = t + 256 * i;
            int r = idx >> 3, c8 = idx & 7;
            *(bf16x8*)&Bs[r][c8 * 8] = *(const bf16x8*)&Wt[(size_t)(n0 + r) * D_ + kt + c8 * 8];
        }
        __syncthreads();
#pragma unroll
        for (int ks = 0; ks < 2; ++ks) {
            bf16x8 a[4], b[4];
#pragma unroll
            for (int m = 0; m < 4; ++m)
                a[m] = *(const bf16x8*)&As[wr * 64 + m * 16 + cl][ks * 32 + g * 8];
#pragma unroll
            for (int n = 0; n < 4; ++n)
                b[n] = *(const bf16x8*)&Bs[wc * 64 + n * 16 + cl][ks * 32 + g * 8];
#pragma unroll
            for (int m = 0; m < 4; ++m)
#pragma unroll
                for (int n = 0; n < 4; ++n)
                    acc[m][n] = __builtin_amdgcn_mfma_f32_16x16x32_bf16(a[m], b[n], acc[m][n], 0, 0, 0);
        }
        __syncthreads();
    }
#pragma unroll
    for (int n = 0; n < 4; ++n) {
        int col = n0 + wc * 64 + n * 16 + cl;
        float bv2 = bias[col];
#pragma unroll
        for (int m = 0; m < 4; ++m) {
            int rowb = m0 + wr * 64 + m * 16 + g * 4;
#pragma unroll
            for (int j = 0; j < 4; ++j)
                dst[(size_t)(rowb + j) * D_ + col] = f2bf(acc[m][n][j] + bv2);
        }
    }
}

// ---------------- V transpose: Vb [B*T][512] -> VtG [(b*8+h)*64+d][T] ----------------
__global__ void vtrans_kernel(const short* __restrict__ Vb, short* __restrict__ VtG) {
    __shared__ short tile[64][72];
    const int t = threadIdx.x;
    const int kt = blockIdx.x & 15;
    const int h  = (blockIdx.x >> 4) & 7;
    const int b  = blockIdx.x >> 7;
#pragma unroll
    for (int i = 0; i < 2; ++i) {
        int idx = t + i * 256;
        int r = idx >> 3, c8 = idx & 7;
        *(bf16x8*)&tile[((r & 7) << 3) | (r >> 3)][c8 * 8] =
            *(const bf16x8*)&Vb[(size_t)(b * T_ + kt * 64 + r) * D_ + h * 64 + c8 * 8];
    }
    __syncthreads();
#pragma unroll
    for (int i = 0; i < 2; ++i) {
        int idx = t + i * 256;
        int d = idx >> 3, r8 = idx & 7;
        bf16x8 pk;
#pragma unroll
        for (int j = 0; j < 8; ++j) pk[j] = tile[(j << 3) | r8][d];
        *(bf16x8*)&VtG[(size_t)((b * 8 + h) * 64 + d) * T_ + kt * 64 + r8 * 8] = pk;
    }
}

// ---------------- flash attention + residual ----------------
// 4 waves, 2 sequential q-tile passes (bx paired with 7-bx): uniform 18 tile-units/block.
// 512 identical blocks = exactly 2/CU, no drain tail. Round-3 proven inner body.
__global__ __launch_bounds__(256, 3) void attn_kernel(
    const short* __restrict__ Qb, const short* __restrict__ Kb,
    const short* __restrict__ VtG, const float* __restrict__ qmask,
    const float* __restrict__ kbias, const float* __restrict__ queries,
    float* __restrict__ out) {
    __shared__ char KV[2][2][8192];      // [buf][K=0 / V^T=1]
    __shared__ short Ps[4][32][72];      // per-wave P tile [q][k]
    const int t = threadIdx.x, lane = t & 63, w = t >> 6;
    const int cl = lane & 15, g = lane >> 4;
    // XCD-grouping remap: 4 blocks sharing (b,h) land on the same XCD
    const int u = blockIdx.x;
    const int wgid = (u & 7) * 64 + (u >> 3);
    const int bx = wgid & 3, h = (wgid >> 2) & 7, b = wgid >> 5;

    // staging source indices (granule XOR pre-permuted: linear LDS dest + XOR read)
    const int rS0 = t >> 3,  cS0 = ((t & 7) ^ (rS0 & 7)) * 8;
    const int t2 = t + 256;
    const int rS1 = t2 >> 3, cS1 = ((t2 & 7) ^ (rS1 & 7)) * 8;
    const short* kS0 = Kb  + ((size_t)(b * T_) + rS0) * D_ + h * 64 + cS0;
    const short* kS1 = Kb  + ((size_t)(b * T_) + rS1) * D_ + h * 64 + cS1;
    const short* vS0 = VtG + (size_t)((b * 8 + h) * 64 + rS0) * T_ + cS0;
    const short* vS1 = VtG + (size_t)((b * 8 + h) * 64 + rS1) * T_ + cS1;
    const float* kbp = kbias + b * T_;
    const float csc = 0.125f * 1.44269504088896f;   // 1/sqrt(64) * log2(e)

    for (int pass = 0; pass < 2; ++pass) {
        const int qtile = pass ? bx : 7 - bx;
        const int qt = qtile * 128;
        const int nt = 2 * qtile + 2;                // always even -> buffer parity safe

        // Q B-fragments: col = q = nq*16+cl, elems d = kc*32+g*8+j
        bf16x8 qb[2][2];
        const int q0 = qt + w * 32 + cl;
#pragma unroll
        for (int nq = 0; nq < 2; ++nq)
#pragma unroll
            for (int kc = 0; kc < 2; ++kc)
                qb[nq][kc] = *(const bf16x8*)&Qb[(size_t)(b * T_ + q0 + nq * 16) * D_ + h * 64 + kc * 32 + g * 8];

        // prologue: stage tile 0 -> buf 0 (disjoint from buf 1 still in use by pass-0 tail)
        gld_lds16(kS0, &KV[0][0][0]    + w * 1024);
        gld_lds16(kS1, &KV[0][0][4096] + w * 1024);
        gld_lds16(vS0, &KV[0][1][0]    + w * 1024);
        gld_lds16(vS1, &KV[0][1][4096] + w * 1024);

        f32x4 o[2][4] = {};
        float m[2] = {-3e30f, -3e30f}, l[2] = {0.f, 0.f};

        for (int it = 0; it < nt; ++it) {
            const int buf = it & 1;
            __syncthreads();   // implicit vmcnt(0): tile staged; all waves done with buf^1

            // key-bias loads FIRST (oldest vmem -> their wait won't drain the prefetch)
            f32x4 kb4[4];
#pragma unroll
            for (int nc = 0; nc < 4; ++nc)
                kb4[nc] = *(const f32x4*)&kbp[it * 64 + nc * 16 + g * 4];

            if (it + 1 < nt) {   // prefetch next tile into buf^1 (flies during compute)
                const int kt2 = (it + 1) * 64;
                char* db = &KV[buf ^ 1][0][0];
                gld_lds16(kS0 + (size_t)kt2 * D_, db + w * 1024);
                gld_lds16(kS1 + (size_t)kt2 * D_, db + 4096 + w * 1024);
                gld_lds16(vS0 + kt2, db + 8192 + w * 1024);
                gld_lds16(vS1 + kt2, db + 8192 + 4096 + w * 1024);
            }

            const char* Kl = &KV[buf][0][0];
            const char* Vl = &KV[buf][1][0];

            // QK^T swapped: s[nq][nc][j] = S[k = nc*16+g*4+j][q = nq*16+cl]
            f32x4 s[2][4] = {};
#pragma unroll
            for (int kc = 0; kc < 2; ++kc)
#pragma unroll
                for (int nc = 0; nc < 4; ++nc) {
                    bf16x8 a = *(const bf16x8*)(Kl + (nc * 16 + cl) * 128 + (((kc * 4 + g) ^ (cl & 7)) << 4));
                    s[0][nc] = __builtin_amdgcn_mfma_f32_16x16x32_bf16(a, qb[0][kc], s[0][nc], 0, 0, 0);
                    s[1][nc] = __builtin_amdgcn_mfma_f32_16x16x32_bf16(a, qb[1][kc], s[1][nc], 0, 0, 0);
                }

            // scale + key bias + causal (last 2 tiles of the pass), lane-local max
            const int kt = it * 64;
            const bool ctile = (it >= 2 * qtile);
            float pm[2] = {-3e30f, -3e30f};
#pragma unroll
            for (int nc = 0; nc < 4; ++nc)
#pragma unroll
                for (int nq = 0; nq < 2; ++nq) {
                    const int qr = qt + w * 32 + nq * 16 + cl;
#pragma unroll
                    for (int j = 0; j < 4; ++j) {
                        float v = fmaf(s[nq][nc][j], csc, kb4[nc][j]);
                        if (ctile && (kt + nc * 16 + g * 4 + j > qr)) v = -3e30f;
                        s[nq][nc][j] = v;
                        pm[nq] = fmaxf(pm[nq], v);
                    }
                }
#pragma unroll
            for (int nq = 0; nq < 2; ++nq) {
                pm[nq] = fmaxf(pm[nq], __shfl_xor(pm[nq], 16));
                pm[nq] = fmaxf(pm[nq], __shfl_xor(pm[nq], 32));
            }
            // defer-max: skip O/l rescale while max grows < 8 (exp2 domain)
            if (__any((pm[0] > m[0] + 8.f) || (pm[1] > m[1] + 8.f))) {
#pragma unroll
                for (int nq = 0; nq < 2; ++nq) {
                    float mn = fmaxf(m[nq], pm[nq]);
                    float cf;
                    asm("v_exp_f32 %0, %1" : "=v"(cf) : "v"(m[nq] - mn));
                    l[nq] *= cf;
                    m[nq] = mn;
#pragma unroll
                    for (int j = 0; j < 4; ++j) {
                        float cfj = __shfl(cf, g * 4 + j);
#pragma unroll
                        for (int dc = 0; dc < 4; ++dc) o[nq][dc][j] *= cfj;
                    }
                }
            }
            float ps[2] = {0.f, 0.f};
#pragma unroll
            for (int nq = 0; nq < 2; ++nq)
#pragma unroll
                for (int nc = 0; nc < 4; ++nc)
#pragma unroll
                    for (int j = 0; j < 4; ++j) {
                        float p;
                        asm("v_exp_f32 %0, %1" : "=v"(p) : "v"(s[nq][nc][j] - m[nq]));
                        s[nq][nc][j] = p;
                        ps[nq] += p;
                    }
#pragma unroll
            for (int nq = 0; nq < 2; ++nq) {
                ps[nq] += __shfl_xor(ps[nq], 16);
                ps[nq] += __shfl_xor(ps[nq], 32);
                l[nq] += ps[nq];
            }

            // P -> per-wave LDS in standard [q][k] order (cvt_pk + b64 writes)
#pragma unroll
            for (int nq = 0; nq < 2; ++nq)
#pragma unroll
                for (int nc = 0; nc < 4; ++nc) {
                    u32x2 pw;
                    asm("v_cvt_pk_bf16_f32 %0, %1, %2" : "=v"(pw[0]) : "v"(s[nq][nc][0]), "v"(s[nq][nc][1]));
                    asm("v_cvt_pk_bf16_f32 %0, %1, %2" : "=v"(pw[1]) : "v"(s[nq][nc][2]), "v"(s[nq][nc][3]));
                    *(u32x2*)&Ps[w][nq * 16 + cl][nc * 16 + g * 4] = pw;
                }

            // PV: A = P (rows q=cl), B = V^T rows d (XOR-swizzled read)
#pragma unroll
            for (int ks = 0; ks < 2; ++ks) {
                bf16x8 pa0 = *(const bf16x8*)&Ps[w][cl][ks * 32 + g * 8];
                bf16x8 pa1 = *(const bf16x8*)&Ps[w][16 + cl][ks * 32 + g * 8];
#pragma unroll
                for (int dc = 0; dc < 4; ++dc) {
                    bf16x8 vv = *(const bf16x8*)(Vl + (dc * 16 + cl) * 128 + (((ks * 4 + g) ^ (cl & 7)) << 4));
                    o[0][dc] = __builtin_amdgcn_mfma_f32_16x16x32_bf16(pa0, vv, o[0][dc], 0, 0, 0);
                    o[1][dc] = __builtin_amdgcn_mfma_f32_16x16x32_bf16(pa1, vv, o[1][dc], 0, 0, 0);
                }
            }
        }

        // epilogue: normalize, query mask, residual
#pragma unroll
        for (int nq = 0; nq < 2; ++nq) {
            float inv = 1.0f / l[nq];
#pragma unroll
            for (int j = 0; j < 4; ++j) {
                float linv = __shfl(inv, g * 4 + j);
                const int q = qt + w * 32 + nq * 16 + g * 4 + j;
                const float sc2 = linv * qmask[b * T_ + q];
                const size_t base = (size_t)(b * T_ + q) * D_ + h * 64;
#pragma unroll
                for (int dc = 0; dc < 4; ++dc) {
                    const size_t idx = base + dc * 16 + cl;
                    out[idx] = o[nq][dc][j] * sc2 + queries[idx];
                }
            }
        }
    }
}

extern "C" void kernel_launch(void* const* d_in, const int* in_sizes, int n_in,
                              void* d_out, int out_size, void* d_ws, size_t ws_size,
                              hipStream_t stream) {
    const float* queries = (const float*)d_in[0];
    const float* keys    = (const float*)d_in[1];
    const float* value   = (const float*)d_in[2];
    const float* Wq      = (const float*)d_in[3];
    const float* bq      = (const float*)d_in[4];
    const float* Wk      = (const float*)d_in[5];
    const float* bk      = (const float*)d_in[6];
    const float* Wv      = (const float*)d_in[7];
    const float* bv      = (const float*)d_in[8];
    float* out = (float*)d_out;

    char* ws = (char*)d_ws;
    const size_t WT_SZ  = (size_t)D_ * D_ * 2;        // 512 KB
    const size_t QKV_SZ = (size_t)B_ * T_ * D_ * 2;   // 16 MB
    short* WtAll = (short*)(ws);
    short* Qb  = (short*)(ws + 3 * WT_SZ);
    short* Kb  = (short*)(ws + 3 * WT_SZ + QKV_SZ);
    short* Vb  = (short*)(ws + 3 * WT_SZ + 2 * QKV_SZ);
    short* VtG = (short*)(ws + 3 * WT_SZ + 3 * QKV_SZ);
    float* qm  = (float*)(ws + 3 * WT_SZ + 4 * QKV_SZ);
    float* kb  = qm + B_ * T_;

    wtrans_kernel<<<dim3(64, 3), 256, 0, stream>>>(Wq, Wk, Wv, WtAll);
    mask_kernel<<<dim3(B_ * T_ / 4, 2), 256, 0, stream>>>(queries, keys, qm, kb);

    proj_gemm<<<dim3(B_ * T_ / 128, D_ / 128, 3), 256, 0, stream>>>(
        queries, keys, value, WtAll, bq, bk, bv, Qb, Kb, Vb);

    vtrans_kernel<<<B_ * H_ * (T_ / 64), 256, 0, stream>>>(Vb, VtG);

    attn_kernel<<<512, 256, 0, stream>>>(Qb, Kb, VtG, qm, kb, queries, out);
}

// Round 6
// 130.354 us; speedup vs baseline: 1.3670x; 1.0086x over previous
//
#include <hip/hip_runtime.h>
#include <hip/hip_bf16.h>

#define B_ 16
#define T_ 1024
#define D_ 512
#define H_ 8
#define M_ (B_ * T_)

typedef __attribute__((ext_vector_type(4))) float f32x4;
typedef __attribute__((ext_vector_type(8))) short bf16x8;
typedef __attribute__((ext_vector_type(4))) short bf16x4;
typedef __attribute__((ext_vector_type(2))) unsigned int u32x2;

__device__ __forceinline__ void gld_lds16(const void* g, void* l) {
    __builtin_amdgcn_global_load_lds((const __attribute__((address_space(1))) void*)g,
                                     (__attribute__((address_space(3))) void*)l, 16, 0, 0);
}

__device__ __forceinline__ short f2bf(float f) {
    union { float f; unsigned u; } v; v.f = f;
    unsigned r = v.u + 0x7FFF + ((v.u >> 16) & 1);
    return (short)(r >> 16);
}

// ---------------- weight transpose: W fp32 [K][N] -> Wt bf16 [N][K], 3 mats ----------------
__global__ void wtrans_kernel(const float* __restrict__ Wq, const float* __restrict__ Wk,
                              const float* __restrict__ Wv, short* __restrict__ WtAll) {
    __shared__ float tile[64][65];
    const int t = threadIdx.x;
    const int mat = blockIdx.y;
    const float* W = (mat == 0) ? Wq : (mat == 1) ? Wk : Wv;
    short* Wt = WtAll + (size_t)mat * D_ * D_;
    const int kt = (blockIdx.x >> 3) * 64;
    const int nt = (blockIdx.x & 7) * 64;
#pragma unroll
    for (int i = 0; i < 4; ++i) {
        int idx = t + i * 256;
        int r = idx >> 4, c4 = idx & 15;
        float4 v = *(const float4*)&W[(kt + r) * D_ + nt + c4 * 4];
        tile[r][c4 * 4 + 0] = v.x; tile[r][c4 * 4 + 1] = v.y;
        tile[r][c4 * 4 + 2] = v.z; tile[r][c4 * 4 + 3] = v.w;
    }
    __syncthreads();
#pragma unroll
    for (int i = 0; i < 2; ++i) {
        int idx = t + i * 256;
        int nr = idx >> 3, c8 = idx & 7;
        bf16x8 pk;
#pragma unroll
        for (int j = 0; j < 8; ++j) pk[j] = f2bf(tile[c8 * 8 + j][nr]);
        *(bf16x8*)&Wt[(nt + nr) * D_ + kt + c8 * 8] = pk;
    }
}

// ---------------- fused convert + masks: X fp32 -> bf16, row-sum masks ----------------
__global__ void cvt_mask_kernel(const float* __restrict__ q, const float* __restrict__ k,
                                const float* __restrict__ v, short* __restrict__ Xbf,
                                float* __restrict__ qm, float* __restrict__ kb) {
    const int w = threadIdx.x >> 6, lane = threadIdx.x & 63;
    const int which = blockIdx.y;
    const int row = blockIdx.x * 4 + w;
    const float* X = (which == 0) ? q : (which == 1) ? k : v;
    short* O = Xbf + (size_t)which * M_ * D_;
    const float4* p = (const float4*)&X[(size_t)row * D_];
    float4 v0 = p[lane], v1 = p[lane + 64];
    float s = v0.x + v0.y + v0.z + v0.w + v1.x + v1.y + v1.z + v1.w;
#pragma unroll
    for (int m = 1; m < 64; m <<= 1) s += __shfl_xor(s, m);
    bf16x4 p0, p1;
    p0[0] = f2bf(v0.x); p0[1] = f2bf(v0.y); p0[2] = f2bf(v0.z); p0[3] = f2bf(v0.w);
    p1[0] = f2bf(v1.x); p1[1] = f2bf(v1.y); p1[2] = f2bf(v1.z); p1[3] = f2bf(v1.w);
    *(bf16x4*)&O[(size_t)row * D_ + lane * 4] = p0;
    *(bf16x4*)&O[(size_t)row * D_ + 256 + lane * 4] = p1;
    if (lane == 0) {
        if (which == 0) qm[row] = (s != 0.0f) ? 1.0f : 0.0f;
        else if (which == 1) kb[row] = (s != 0.0f) ? 0.0f : -3e30f;
    }
}

// ---------------- projection GEMM, pure bf16 (m97 structure, gld_lds staging) ----------------
// grid: (n-tile=4, m-tile=128, mat=3). XOR-pre-permuted sources, conflict-free b128 reads.
__global__ __launch_bounds__(256) void proj_gemm_bf(
    const short* __restrict__ Xbf, const short* __restrict__ WtAll,
    const float* __restrict__ bq, const float* __restrict__ bk, const float* __restrict__ bv,
    short* __restrict__ QKV) {
    __shared__ char As[16384];
    __shared__ char Bs[16384];
    const int t = threadIdx.x;
    const int mat = blockIdx.z;
    const short* X  = Xbf + (size_t)mat * M_ * D_;
    const short* Wt = WtAll + (size_t)mat * D_ * D_;
    const float* bias = (mat == 0) ? bq : (mat == 1) ? bk : bv;
    short* dst = QKV + (size_t)mat * M_ * D_;
    const int n0 = blockIdx.x * 128, m0 = blockIdx.y * 128;
    const int lane = t & 63, w = t >> 6;
    const int wr = w >> 1, wc = w & 1;
    const int cl = lane & 15, g = lane >> 4;

    // staging: dest granule gi = t + i*256 -> source (row gi>>3, col-granule (gi&7)^(row&7))
    const int r0 = t >> 3, c0 = ((t & 7) ^ (r0 & 7)) * 8;
    const short* sA = X  + (size_t)(m0 + r0) * D_ + c0;
    const short* sB = Wt + (size_t)(n0 + r0) * D_ + c0;

    f32x4 acc[4][4] = {};
    // prologue: stage kt=0
#pragma unroll
    for (int i = 0; i < 4; ++i) {
        gld_lds16(sA + (size_t)(32 * i) * D_, As + t * 16 + i * 4096);
        gld_lds16(sB + (size_t)(32 * i) * D_, Bs + t * 16 + i * 4096);
    }
    for (int kt = 0; kt < D_; kt += 64) {
        __syncthreads();   // implicit vmcnt(0): tile staged
#pragma unroll
        for (int ks = 0; ks < 2; ++ks) {
            bf16x8 a[4], b[4];
#pragma unroll
            for (int m = 0; m < 4; ++m)
                a[m] = *(const bf16x8*)(As + (wr * 64 + m * 16 + cl) * 128 + (((ks * 4 + g) ^ (cl & 7)) << 4));
#pragma unroll
            for (int n = 0; n < 4; ++n)
                b[n] = *(const bf16x8*)(Bs + (wc * 64 + n * 16 + cl) * 128 + (((ks * 4 + g) ^ (cl & 7)) << 4));
#pragma unroll
            for (int m = 0; m < 4; ++m)
#pragma unroll
                for (int n = 0; n < 4; ++n)
                    acc[m][n] = __builtin_amdgcn_mfma_f32_16x16x32_bf16(a[m], b[n], acc[m][n], 0, 0, 0);
        }
        __syncthreads();   // all waves done reading before restage
        if (kt + 64 < D_) {
            const int k2 = kt + 64;
#pragma unroll
            for (int i = 0; i < 4; ++i) {
                gld_lds16(sA + (size_t)(32 * i) * D_ + k2, As + t * 16 + i * 4096);
                gld_lds16(sB + (size_t)(32 * i) * D_ + k2, Bs + t * 16 + i * 4096);
            }
        }
    }
#pragma unroll
    for (int n = 0; n < 4; ++n) {
        int col = n0 + wc * 64 + n * 16 + cl;
        float bv2 = bias[col];
#pragma unroll
        for (int m = 0; m < 4; ++m) {
            int rowb = m0 + wr * 64 + m * 16 + g * 4;
#pragma unroll
            for (int j = 0; j < 4; ++j)
                dst[(size_t)(rowb + j) * D_ + col] = f2bf(acc[m][n][j] + bv2);
        }
    }
}

// ---------------- fallback projection GEMM (fp32 X, in-kernel conversion) ----------------
__global__ __launch_bounds__(256) void proj_gemm(
    const float* __restrict__ Xq, const float* __restrict__ Xk, const float* __restrict__ Xv,
    const short* __restrict__ WtAll,
    const float* __restrict__ bq, const float* __restrict__ bk, const float* __restrict__ bv,
    short* __restrict__ Qb, short* __restrict__ Kb, short* __restrict__ Vb) {
    __shared__ short As2[128][72];
    __shared__ short Bs2[128][72];
    const int t = threadIdx.x;
    const int mat = blockIdx.z;
    const float* X = (mat == 0) ? Xq : (mat == 1) ? Xk : Xv;
    const short* Wt = WtAll + (size_t)mat * D_ * D_;
    const float* bias = (mat == 0) ? bq : (mat == 1) ? bk : bv;
    short* dst = (mat == 0) ? Qb : (mat == 1) ? Kb : Vb;
    const int m0 = blockIdx.x * 128, n0 = blockIdx.y * 128;
    const int lane = t & 63, w = t >> 6;
    const int wr = w >> 1, wc = w & 1;
    const int cl = lane & 15, g = lane >> 4;
    f32x4 acc[4][4] = {};
    for (int kt = 0; kt < D_; kt += 64) {
#pragma unroll
        for (int i = 0; i < 8; ++i) {
            int idx = t + 256 * i;
            int r = idx >> 4, c4 = idx & 15;
            float4 v = *(const float4*)&X[(size_t)(m0 + r) * D_ + kt + c4 * 4];
            bf16x4 pk;
            pk[0] = f2bf(v.x); pk[1] = f2bf(v.y); pk[2] = f2bf(v.z); pk[3] = f2bf(v.w);
            *(bf16x4*)&As2[r][c4 * 4] = pk;
        }
#pragma unroll
        for (int i = 0; i < 4; ++i) {
            int idx = t + 256 * i;
            int r = idx >> 3, c8 = idx & 7;
            *(bf16x8*)&Bs2[r][c8 * 8] = *(const bf16x8*)&Wt[(size_t)(n0 + r) * D_ + kt + c8 * 8];
        }
        __syncthreads();
#pragma unroll
        for (int ks = 0; ks < 2; ++ks) {
            bf16x8 a[4], b[4];
#pragma unroll
            for (int m = 0; m < 4; ++m)
                a[m] = *(const bf16x8*)&As2[wr * 64 + m * 16 + cl][ks * 32 + g * 8];
#pragma unroll
            for (int n = 0; n < 4; ++n)
                b[n] = *(const bf16x8*)&Bs2[wc * 64 + n * 16 + cl][ks * 32 + g * 8];
#pragma unroll
            for (int m = 0; m < 4; ++m)
#pragma unroll
                for (int n = 0; n < 4; ++n)
                    acc[m][n] = __builtin_amdgcn_mfma_f32_16x16x32_bf16(a[m], b[n], acc[m][n], 0, 0, 0);
        }
        __syncthreads();
    }
#pragma unroll
    for (int n = 0; n < 4; ++n) {
        int col = n0 + wc * 64 + n * 16 + cl;
        float bv2 = bias[col];
#pragma unroll
        for (int m = 0; m < 4; ++m) {
            int rowb = m0 + wr * 64 + m * 16 + g * 4;
#pragma unroll
            for (int j = 0; j < 4; ++j)
                dst[(size_t)(rowb + j) * D_ + col] = f2bf(acc[m][n][j] + bv2);
        }
    }
}

// ---------------- fallback masks ----------------
__global__ void mask_kernel(const float* __restrict__ queries, const float* __restrict__ keys,
                            float* __restrict__ qm, float* __restrict__ kb) {
    const int w = threadIdx.x >> 6, lane = threadIdx.x & 63;
    const int row = blockIdx.x * 4 + w;
    const int which = blockIdx.y;
    const float* X = which ? keys : queries;
    const float4* p = (const float4*)&X[(size_t)row * D_];
    float s = 0.f;
#pragma unroll
    for (int i = 0; i < 2; ++i) {
        float4 v = p[lane + 64 * i];
        s += v.x + v.y + v.z + v.w;
    }
#pragma unroll
    for (int m = 1; m < 64; m <<= 1) s += __shfl_xor(s, m);
    if (lane == 0) {
        if (which) kb[row] = (s != 0.0f) ? 0.0f : -3e30f;
        else       qm[row] = (s != 0.0f) ? 1.0f : 0.0f;
    }
}

// ---------------- V transpose: Vb [B*T][512] -> VtG [(b*8+h)*64+d][T] ----------------
__global__ void vtrans_kernel(const short* __restrict__ Vb, short* __restrict__ VtG) {
    __shared__ short tile[64][72];
    const int t = threadIdx.x;
    const int kt = blockIdx.x & 15;
    const int h  = (blockIdx.x >> 4) & 7;
    const int b  = blockIdx.x >> 7;
#pragma unroll
    for (int i = 0; i < 2; ++i) {
        int idx = t + i * 256;
        int r = idx >> 3, c8 = idx & 7;
        *(bf16x8*)&tile[((r & 7) << 3) | (r >> 3)][c8 * 8] =
            *(const bf16x8*)&Vb[(size_t)(b * T_ + kt * 64 + r) * D_ + h * 64 + c8 * 8];
    }
    __syncthreads();
#pragma unroll
    for (int i = 0; i < 2; ++i) {
        int idx = t + i * 256;
        int d = idx >> 3, r8 = idx & 7;
        bf16x8 pk;
#pragma unroll
        for (int j = 0; j < 8; ++j) pk[j] = tile[(j << 3) | r8][d];
        *(bf16x8*)&VtG[(size_t)((b * 8 + h) * 64 + d) * T_ + kt * 64 + r8 * 8] = pk;
    }
}

// ---------------- flash attention + residual (round-5 proven) ----------------
__global__ __launch_bounds__(256, 3) void attn_kernel(
    const short* __restrict__ Qb, const short* __restrict__ Kb,
    const short* __restrict__ VtG, const float* __restrict__ qmask,
    const float* __restrict__ kbias, const float* __restrict__ queries,
    float* __restrict__ out) {
    __shared__ char KV[2][2][8192];      // [buf][K=0 / V^T=1]
    __shared__ short Ps[4][32][72];      // per-wave P tile [q][k]
    const int t = threadIdx.x, lane = t & 63, w = t >> 6;
    const int cl = lane & 15, g = lane >> 4;
    const int u = blockIdx.x;
    const int wgid = (u & 7) * 64 + (u >> 3);
    const int bx = wgid & 3, h = (wgid >> 2) & 7, b = wgid >> 5;

    const int rS0 = t >> 3,  cS0 = ((t & 7) ^ (rS0 & 7)) * 8;
    const int t2 = t + 256;
    const int rS1 = t2 >> 3, cS1 = ((t2 & 7) ^ (rS1 & 7)) * 8;
    const short* kS0 = Kb  + ((size_t)(b * T_) + rS0) * D_ + h * 64 + cS0;
    const short* kS1 = Kb  + ((size_t)(b * T_) + rS1) * D_ + h * 64 + cS1;
    const short* vS0 = VtG + (size_t)((b * 8 + h) * 64 + rS0) * T_ + cS0;
    const short* vS1 = VtG + (size_t)((b * 8 + h) * 64 + rS1) * T_ + cS1;
    const float* kbp = kbias + b * T_;
    const float csc = 0.125f * 1.44269504088896f;

    for (int pass = 0; pass < 2; ++pass) {
        const int qtile = pass ? bx : 7 - bx;
        const int qt = qtile * 128;
        const int nt = 2 * qtile + 2;

        bf16x8 qb[2][2];
        const int q0 = qt + w * 32 + cl;
#pragma unroll
        for (int nq = 0; nq < 2; ++nq)
#pragma unroll
            for (int kc = 0; kc < 2; ++kc)
                qb[nq][kc] = *(const bf16x8*)&Qb[(size_t)(b * T_ + q0 + nq * 16) * D_ + h * 64 + kc * 32 + g * 8];

        gld_lds16(kS0, &KV[0][0][0]    + w * 1024);
        gld_lds16(kS1, &KV[0][0][4096] + w * 1024);
        gld_lds16(vS0, &KV[0][1][0]    + w * 1024);
        gld_lds16(vS1, &KV[0][1][4096] + w * 1024);

        f32x4 o[2][4] = {};
        float m[2] = {-3e30f, -3e30f}, l[2] = {0.f, 0.f};

        for (int it = 0; it < nt; ++it) {
            const int buf = it & 1;
            __syncthreads();

            f32x4 kb4[4];
#pragma unroll
            for (int nc = 0; nc < 4; ++nc)
                kb4[nc] = *(const f32x4*)&kbp[it * 64 + nc * 16 + g * 4];

            if (it + 1 < nt) {
                const int kt2 = (it + 1) * 64;
                char* db = &KV[buf ^ 1][0][0];
                gld_lds16(kS0 + (size_t)kt2 * D_, db + w * 1024);
                gld_lds16(kS1 + (size_t)kt2 * D_, db + 4096 + w * 1024);
                gld_lds16(vS0 + kt2, db + 8192 + w * 1024);
                gld_lds16(vS1 + kt2, db + 8192 + 4096 + w * 1024);
            }

            const char* Kl = &KV[buf][0][0];
            const char* Vl = &KV[buf][1][0];

            f32x4 s[2][4] = {};
#pragma unroll
            for (int kc = 0; kc < 2; ++kc)
#pragma unroll
                for (int nc = 0; nc < 4; ++nc) {
                    bf16x8 a = *(const bf16x8*)(Kl + (nc * 16 + cl) * 128 + (((kc * 4 + g) ^ (cl & 7)) << 4));
                    s[0][nc] = __builtin_amdgcn_mfma_f32_16x16x32_bf16(a, qb[0][kc], s[0][nc], 0, 0, 0);
                    s[1][nc] = __builtin_amdgcn_mfma_f32_16x16x32_bf16(a, qb[1][kc], s[1][nc], 0, 0, 0);
                }

            const int kt = it * 64;
            const bool ctile = (it >= 2 * qtile);
            float pm[2] = {-3e30f, -3e30f};
#pragma unroll
            for (int nc = 0; nc < 4; ++nc)
#pragma unroll
                for (int nq = 0; nq < 2; ++nq) {
                    const int qr = qt + w * 32 + nq * 16 + cl;
#pragma unroll
                    for (int j = 0; j < 4; ++j) {
                        float v = fmaf(s[nq][nc][j], csc, kb4[nc][j]);
                        if (ctile && (kt + nc * 16 + g * 4 + j > qr)) v = -3e30f;
                        s[nq][nc][j] = v;
                        pm[nq] = fmaxf(pm[nq], v);
                    }
                }
#pragma unroll
            for (int nq = 0; nq < 2; ++nq) {
                pm[nq] = fmaxf(pm[nq], __shfl_xor(pm[nq], 16));
                pm[nq] = fmaxf(pm[nq], __shfl_xor(pm[nq], 32));
            }
            if (__any((pm[0] > m[0] + 8.f) || (pm[1] > m[1] + 8.f))) {
#pragma unroll
                for (int nq = 0; nq < 2; ++nq) {
                    float mn = fmaxf(m[nq], pm[nq]);
                    float cf;
                    asm("v_exp_f32 %0, %1" : "=v"(cf) : "v"(m[nq] - mn));
                    l[nq] *= cf;
                    m[nq] = mn;
#pragma unroll
                    for (int j = 0; j < 4; ++j) {
                        float cfj = __shfl(cf, g * 4 + j);
#pragma unroll
                        for (int dc = 0; dc < 4; ++dc) o[nq][dc][j] *= cfj;
                    }
                }
            }
            float ps[2] = {0.f, 0.f};
#pragma unroll
            for (int nq = 0; nq < 2; ++nq)
#pragma unroll
                for (int nc = 0; nc < 4; ++nc)
#pragma unroll
                    for (int j = 0; j < 4; ++j) {
                        float p;
                        asm("v_exp_f32 %0, %1" : "=v"(p) : "v"(s[nq][nc][j] - m[nq]));
                        s[nq][nc][j] = p;
                        ps[nq] += p;
                    }
#pragma unroll
            for (int nq = 0; nq < 2; ++nq) {
                ps[nq] += __shfl_xor(ps[nq], 16);
                ps[nq] += __shfl_xor(ps[nq], 32);
                l[nq] += ps[nq];
            }

#pragma unroll
            for (int nq = 0; nq < 2; ++nq)
#pragma unroll
                for (int nc = 0; nc < 4; ++nc) {
                    u32x2 pw;
                    asm("v_cvt_pk_bf16_f32 %0, %1, %2" : "=v"(pw[0]) : "v"(s[nq][nc][0]), "v"(s[nq][nc][1]));
                    asm("v_cvt_pk_bf16_f32 %0, %1, %2" : "=v"(pw[1]) : "v"(s[nq][nc][2]), "v"(s[nq][nc][3]));
                    *(u32x2*)&Ps[w][nq * 16 + cl][nc * 16 + g * 4] = pw;
                }

#pragma unroll
            for (int ks = 0; ks < 2; ++ks) {
                bf16x8 pa0 = *(const bf16x8*)&Ps[w][cl][ks * 32 + g * 8];
                bf16x8 pa1 = *(const bf16x8*)&Ps[w][16 + cl][ks * 32 + g * 8];
#pragma unroll
                for (int dc = 0; dc < 4; ++dc) {
                    bf16x8 vv = *(const bf16x8*)(Vl + (dc * 16 + cl) * 128 + (((ks * 4 + g) ^ (cl & 7)) << 4));
                    o[0][dc] = __builtin_amdgcn_mfma_f32_16x16x32_bf16(pa0, vv, o[0][dc], 0, 0, 0);
                    o[1][dc] = __builtin_amdgcn_mfma_f32_16x16x32_bf16(pa1, vv, o[1][dc], 0, 0, 0);
                }
            }
        }

#pragma unroll
        for (int nq = 0; nq < 2; ++nq) {
            float inv = 1.0f / l[nq];
#pragma unroll
            for (int j = 0; j < 4; ++j) {
                float linv = __shfl(inv, g * 4 + j);
                const int q = qt + w * 32 + nq * 16 + g * 4 + j;
                const float sc2 = linv * qmask[b * T_ + q];
                const size_t base = (size_t)(b * T_ + q) * D_ + h * 64;
#pragma unroll
                for (int dc = 0; dc < 4; ++dc) {
                    const size_t idx = base + dc * 16 + cl;
                    out[idx] = o[nq][dc][j] * sc2 + queries[idx];
                }
            }
        }
    }
}

extern "C" void kernel_launch(void* const* d_in, const int* in_sizes, int n_in,
                              void* d_out, int out_size, void* d_ws, size_t ws_size,
                              hipStream_t stream) {
    const float* queries = (const float*)d_in[0];
    const float* keys    = (const float*)d_in[1];
    const float* value   = (const float*)d_in[2];
    const float* Wq      = (const float*)d_in[3];
    const float* bq      = (const float*)d_in[4];
    const float* Wk      = (const float*)d_in[5];
    const float* bk      = (const float*)d_in[6];
    const float* Wv      = (const float*)d_in[7];
    const float* bv      = (const float*)d_in[8];
    float* out = (float*)d_out;

    char* ws = (char*)d_ws;
    const size_t WT_SZ  = (size_t)D_ * D_ * 2;        // per-mat 512 KB
    const size_t XB_SZ  = (size_t)M_ * D_ * 2;        // per-mat 16 MB

    const size_t NEED = 3 * WT_SZ + 6 * XB_SZ + 2 * (size_t)M_ * 4;
    if (ws_size >= NEED) {
        // fast path: pre-converted bf16 inputs, gld_lds GEMM
        short* WtAll = (short*)(ws);
        short* Xbf   = (short*)(ws + 3 * WT_SZ);
        short* QKV   = (short*)(ws + 3 * WT_SZ + 3 * XB_SZ);
        short* Qb = QKV, *Kb = QKV + M_ * D_, *Vb = QKV + 2 * (size_t)M_ * D_;
        short* VtG   = Xbf;                      // aliases dead Xq region post-GEMM
        float* qm    = (float*)(ws + 3 * WT_SZ + 6 * XB_SZ);
        float* kb    = qm + M_;

        wtrans_kernel<<<dim3(64, 3), 256, 0, stream>>>(Wq, Wk, Wv, WtAll);
        cvt_mask_kernel<<<dim3(M_ / 4, 3), 256, 0, stream>>>(queries, keys, value, Xbf, qm, kb);
        proj_gemm_bf<<<dim3(D_ / 128, M_ / 128, 3), 256, 0, stream>>>(
            Xbf, WtAll, bq, bk, bv, QKV);
        vtrans_kernel<<<B_ * H_ * (T_ / 64), 256, 0, stream>>>(Vb, VtG);
        attn_kernel<<<512, 256, 0, stream>>>(Qb, Kb, VtG, qm, kb, queries, out);
    } else {
        // fallback: round-5 path
        short* WtAll = (short*)(ws);
        short* Qb  = (short*)(ws + 3 * WT_SZ);
        short* Kb  = (short*)(ws + 3 * WT_SZ + XB_SZ);
        short* Vb  = (short*)(ws + 3 * WT_SZ + 2 * XB_SZ);
        short* VtG = (short*)(ws + 3 * WT_SZ + 3 * XB_SZ);
        float* qm  = (float*)(ws + 3 * WT_SZ + 4 * XB_SZ);
        float* kb  = qm + M_;

        wtrans_kernel<<<dim3(64, 3), 256, 0, stream>>>(Wq, Wk, Wv, WtAll);
        mask_kernel<<<dim3(M_ / 4, 2), 256, 0, stream>>>(queries, keys, qm, kb);
        proj_gemm<<<dim3(M_ / 128, D_ / 128, 3), 256, 0, stream>>>(
            queries, keys, value, WtAll, bq, bk, bv, Qb, Kb, Vb);
        vtrans_kernel<<<B_ * H_ * (T_ / 64), 256, 0, stream>>>(Vb, VtG);
        attn_kernel<<<512, 256, 0, stream>>>(Qb, Kb, VtG, qm, kb, queries, out);
    }
}